// Round 12
// baseline (43.688 us; speedup 1.0000x reference)
//
#include <hip/hip_runtime.h>
#include <float.h>

// ROI adaptive max-pool 7x7. features [512,64,64] fp32, 1024 ROIs.
// Phase 1: transpose features to [H][W][C] in d_ws, block id = bs*8+bc so
//   channel slice [64bc,64bc+64) is WRITTEN by XCD bc (R9-proven locality).
// Phase 2: wave = (roi, 32 channels). ROW-PAIR SPLIT: lanes 0-31 = channels
//   at EVEN rows, lanes 32-63 = same channels at ODD rows -> the serial
//   dependent row chain halves (ceil(hl/2) iterations), waves double to
//   16384 for TLP. Per-pair fold: uniform guard on bins touching the pair,
//   per-lane cndmask inside (phantom row y2+1 is clamp-loaded, predicate-
//   excluded). Merge halves via 49x shfl_xor(32)+max. Single-round LDS
//   transpose epilogue (both halves deposit disjoint bin ranges), dense
//   non-temporal dwordx4 stores (R11-proven).
constexpr int CC = 512, HH = 64, WW = 64, HW = HH * WW;
#define NEG (-FLT_MAX)
typedef float f4 __attribute__((ext_vector_type(4)));

// ---------- phase 1: [C][HW] -> [HW][C], XCD-keyed by channel chunk ----------
__global__ __launch_bounds__(256) void transpose_kernel(
    const float* __restrict__ f, float* __restrict__ ft)
{
    __shared__ float tile[64][65];
    int bc = blockIdx.x & 7;             // channel slice -> XCD bc
    int bs = blockIdx.x >> 3;            // hw tile (4096/64)
    int tx = threadIdx.x & 63, ty0 = threadIdx.x >> 6;
#pragma unroll
    for (int k = 0; k < 16; ++k) {
        int c = k * 4 + ty0;
        tile[c][tx] = __builtin_nontemporal_load(
            &f[(size_t)(bc * 64 + c) * HW + bs * 64 + tx]);          // read-once
    }
    __syncthreads();
#pragma unroll
    for (int k = 0; k < 16; ++k) {
        int s = k * 4 + ty0;
        ft[(size_t)(bs * 64 + s) * CC + bc * 64 + tx] = tile[tx][s]; // cached: pool re-reads
    }
}

// static per-bin cell ranges: bin j only touches cells
// k in [floor(2j/7), ceil(9(j+1)/7)) for w_len in [2,9] -> 36 terms total.
#define KMIN(j) ((2 * (j)) / 7)
#define KMAX(j) ((9 * ((j) + 1) + 6) / 7)

// ---------- phase 2: pool from [HW][C] ----------
__global__ __launch_bounds__(256) void pool_kernel(
    const float* __restrict__ ft,        // [H][W][C]
    const int4*  __restrict__ rois,      // [R] (x1,y1,x2,y2) image px
    float* __restrict__ out,             // [R,C,7,7]
    int nblocks)
{
    __shared__ __align__(16) float lds[4][32 * 49];
    int wslot = threadIdx.x >> 6;
    int b = __builtin_amdgcn_readfirstlane(blockIdx.x);
    if (b >= nblocks) return;
    int lane = threadIdx.x & 63;
    int ch   = lane & 31;                // channel within 32-chunk
    int half = lane >> 5;                // 0: even rows, 1: odd rows

    int x = b & 7;                       // XCD; owns channel slice [64x,64x+64)
    int g = b >> 3;                      // 0..511
    int u = g * 4 + wslot;               // unit within XCD: 0..2047
    int r     = u >> 1;                  // ROI
    int chunk = 2 * x + (u & 1);         // 32-channel chunk 0..15
    int c0    = chunk << 5;

    int4 roi = rois[r];                  // uniform -> s_load
    // (px * 1/16.f) truncated == px >> 4 for px in [0,1024): exact in fp32.
    int x1 = roi.x >> 4, y1 = roi.y >> 4, x2 = roi.z >> 4, y2 = roi.w >> 4;
    int hl = y2 - y1 + 1, wl = x2 - x1 + 1;   // 2..9 each (bw,bh >= 16 px)

    // torch adaptive bins (uniform -> SGPR): [floor(i*L/7), ceil((i+1)*L/7)).
    int hs[7], he[7], s_[7], e_[7];
#pragma unroll
    for (int i = 0; i < 7; ++i) {
        hs[i] = y1 + (i * hl) / 7;
        he[i] = y1 + ((i + 1) * hl + 6) / 7;
        s_[i] = (i * wl) / 7;                 // cell index relative to x1
        e_[i] = ((i + 1) * wl + 6) / 7;
    }

    float acc[7][7];
#pragma unroll
    for (int i = 0; i < 7; ++i)
#pragma unroll
        for (int j = 0; j < 7; ++j) acc[i][j] = NEG;

    // Per-lane row offset (floats): half 1 reads the next row. On an odd-hl
    // last pair the odd row would be y2+1 (OOB/phantom): clamp to y2 — the
    // load is harmless (dup of even row) and the fold predicate excludes it.
    int loff_n = ch + half * (WW * CC);
    int loff_l = (hl & 1) ? ch : loff_n;

    int T = (hl + 1) >> 1;               // row pairs (uniform)
    for (int t = 0; t < T; ++t) {
        int h0 = y1 + 2 * t;             // even row of the pair (uniform)
        const float* rowp = ft + c0 + (size_t)h0 * (WW * CC)
                          + ((t == T - 1) ? loff_l : loff_n);
        float v[9];
#pragma unroll
        for (int k = 0; k < 9; ++k) {
            v[k] = NEG;
            if (k < wl)                  // uniform scalar branch
                v[k] = rowp[(x1 + k) * CC];
        }
        float m[7];
#pragma unroll
        for (int j = 0; j < 7; ++j) {    // static 36-term tree (R6-proven)
            float a = NEG;
#pragma unroll
            for (int k = KMIN(j); k < KMAX(j); ++k) {
                bool p = (k >= s_[j]) && (k < e_[j]);   // uniform
                a = fmaxf(a, p ? v[k] : NEG);
            }
            m[j] = a;
        }
        int h = h0 + half;               // this lane's logical row (may be y2+1)
#pragma unroll
        for (int i = 0; i < 7; ++i) {
            if (he[i] > h0 && hs[i] <= h0 + 1) {   // uniform: bin touches pair
                bool in = (h >= hs[i]) && (h < he[i]);  // per-lane (cndmask)
#pragma unroll
                for (int j = 0; j < 7; ++j)
                    acc[i][j] = fmaxf(acc[i][j], in ? m[j] : NEG);
            }
        }
    }

    // Merge even/odd halves: lanes l and l+32 hold the same channel.
#pragma unroll
    for (int i = 0; i < 7; ++i)
#pragma unroll
        for (int j = 0; j < 7; ++j) {
            float o = __shfl_xor(acc[i][j], 32, 64);
            acc[i][j] = fmaxf(acc[i][j], o);
        }

    // Single-round LDS transpose: half 0 deposits bins 0..27, half 1 bins
    // 28..48 (both halves hold identical merged acc). Stride 49: conflict-free.
    float* L = lds[wslot];
#pragma unroll
    for (int i = 0; i < 7; ++i) {
        if ((i >= 4) == (half != 0)) {
#pragma unroll
            for (int j = 0; j < 7; ++j)
                L[ch * 49 + i * 7 + j] = acc[i][j];
        }
    }
    asm volatile("s_waitcnt lgkmcnt(0)" ::: "memory");

    float* og = out + ((size_t)r * CC + c0) * 49;   // 1568 floats contiguous
#pragma unroll
    for (int s = 0; s < 6; ++s) {        // 6 x (64 lanes x dwordx4) = 1536
        int idx = s * 64 + lane;
        __builtin_nontemporal_store(*(const f4*)(L + idx * 4),
                                    (f4*)(og + idx * 4));
    }
    if (lane < 8) {                      // 392 = 6*64 + 8 tail
        int idx = 384 + lane;
        __builtin_nontemporal_store(*(const f4*)(L + idx * 4),
                                    (f4*)(og + idx * 4));
    }
}

// ---------- fallback (R4, proven): used only if ws_size < 8 MB ----------
__global__ __launch_bounds__(256) void roi_pool_direct(
    const float* __restrict__ features, const int4* __restrict__ rois,
    float* __restrict__ out, int ngroups)
{
    int wid = __builtin_amdgcn_readfirstlane(
        blockIdx.x * (blockDim.x >> 6) + (threadIdx.x >> 6));
    if (wid >= ngroups) return;
    int lane = threadIdx.x & 63;
    if (lane >= 49) return;
    int r = wid >> 4, c0 = (wid & 15) * 32;
    int4 roi = rois[r];
    int x1 = roi.x >> 4, y1 = roi.y >> 4, x2 = roi.z >> 4, y2 = roi.w >> 4;
    int h_len = y2 - y1 + 1, w_len = x2 - x1 + 1;
    int oh = lane / 7, ow = lane - oh * 7;
    int hs = y1 + (oh * h_len) / 7, he = y1 + ((oh + 1) * h_len + 6) / 7;
    int ws = x1 + (ow * w_len) / 7, we = x1 + ((ow + 1) * w_len + 6) / 7;
    int wlst = we - 1;
    int wa = ws, wb = min(ws + 1, wlst), wc = min(ws + 2, wlst);
    bool need1 = hs + 1 < he, need2 = hs + 2 < he;
    int o0 = (hs * WW + wa) * 4, o0b = (hs * WW + wb) * 4, o0c = (hs * WW + wc) * 4;
    const char* fb = (const char*)features + (size_t)c0 * (HW * 4);
    float* ob = out + ((size_t)r * CC + c0) * 49 + lane;
#pragma unroll 4
    for (int j = 0; j < 32; ++j) {
        float a = fmaxf(fmaxf(*(const float*)(fb + o0),
                              *(const float*)(fb + o0b)),
                        *(const float*)(fb + o0c));
        if (need1) {
            a = fmaxf(a, fmaxf(fmaxf(*(const float*)(fb + o0 + WW * 4),
                                     *(const float*)(fb + o0b + WW * 4)),
                               *(const float*)(fb + o0c + WW * 4)));
        }
        if (need2) {
            a = fmaxf(a, fmaxf(fmaxf(*(const float*)(fb + o0 + 2 * WW * 4),
                                     *(const float*)(fb + o0b + 2 * WW * 4)),
                               *(const float*)(fb + o0c + 2 * WW * 4)));
        }
        *ob = a;
        fb += HW * 4;
        ob += 49;
    }
}

extern "C" void kernel_launch(void* const* d_in, const int* in_sizes, int n_in,
                              void* d_out, int out_size, void* d_ws, size_t ws_size,
                              hipStream_t stream) {
    const float* features = (const float*)d_in[0];   // [1,512,64,64] fp32
    const int4*  rois     = (const int4*)d_in[1];    // [R,4] int32
    float* out = (float*)d_out;
    int R = out_size / (CC * 49);                    // 1024

    if (ws_size >= (size_t)CC * HW * sizeof(float)) {
        float* ft = (float*)d_ws;                    // [HW][C], 8 MB
        transpose_kernel<<<512, 256, 0, stream>>>(features, ft);
        int nblocks = (R * 16 / 2) / 4 * 2;          // 16384 waves / 4 = 4096
        nblocks = 4096;
        pool_kernel<<<nblocks, 256, 0, stream>>>(ft, rois, out, nblocks);
    } else {
        int ngroups = R * 16;
        roi_pool_direct<<<(ngroups + 3) / 4, 256, 0, stream>>>(features, rois, out, ngroups);
    }
}

// Round 13
// 31.774 us; speedup vs baseline: 1.3749x; 1.3749x over previous
//
#include <hip/hip_runtime.h>
#include <float.h>

// ROI adaptive max-pool 7x7. features [512,64,64] fp32, 1024 ROIs.
// == R11 champion (33.8us) + ONE delta: the pool row loop is template-
// specialized on the wave-uniform w_len (WL in 2..9, switch dispatch).
// With WL compile-time, every w-bin window [floor(j*WL/7), ceil((j+1)WL/7))
// is a CONSTANT -> m[7] is a minimal fmax tree (<=8 fmax, no cndmasks, no
// predicates), exactly WL loads per row, and the 14 w-bin divisions vanish.
// Phase 1: transpose features to [H][W][C] in d_ws, block id = bs*8+bc so
//   channel slice bc is WRITTEN by XCD bc (R9-proven L2 co-location).
// Phase 2: pool; block id = g*8+bc, 4 waves = 4 ROIs x the SAME 64-channel
//   chunk -> ft reads hit local XCD L2. Non-temporal output stores
//   (R11-proven: out is never re-read, must not evict ft from L2).
constexpr int CC = 512, HH = 64, WW = 64, HW = HH * WW;
#define NEG (-FLT_MAX)
typedef float f4 __attribute__((ext_vector_type(4)));

// ---------- phase 1: [C][HW] -> [HW][C], XCD-keyed by channel chunk ----------
__global__ __launch_bounds__(256) void transpose_kernel(
    const float* __restrict__ f, float* __restrict__ ft)
{
    __shared__ float tile[64][65];
    int bc = blockIdx.x & 7;             // channel slice -> XCD bc
    int bs = blockIdx.x >> 3;            // hw tile (4096/64)
    int tx = threadIdx.x & 63, ty0 = threadIdx.x >> 6;
#pragma unroll
    for (int k = 0; k < 16; ++k) {
        int c = k * 4 + ty0;
        tile[c][tx] = __builtin_nontemporal_load(
            &f[(size_t)(bc * 64 + c) * HW + bs * 64 + tx]);          // read-once
    }
    __syncthreads();
#pragma unroll
    for (int k = 0; k < 16; ++k) {
        int s = k * 4 + ty0;
        ft[(size_t)(bs * 64 + s) * CC + bc * 64 + tx] = tile[tx][s]; // cached: pool re-reads
    }
}

// ---------- WL-specialized row loop: windows are compile-time ----------
template <int WL>
__device__ __forceinline__ void pool_rows(
    const float* __restrict__ fbase,     // ft + c0 + lane
    int y1, int y2, int x1,
    const int (&hs)[7], const int (&he)[7],
    float (&acc)[7][7])
{
    for (int h = y1; h <= y2; ++h) {     // uniform, 2..9 iters
        const float* rowp = fbase + (size_t)h * (WW * CC);
        float v[WL];
#pragma unroll
        for (int k = 0; k < WL; ++k)     // exactly WL coalesced loads
            v[k] = rowp[(x1 + k) * CC];
        float m[7];
#pragma unroll
        for (int j = 0; j < 7; ++j) {    // constant windows: pure fmax tree
            const int s = (j * WL) / 7;
            const int e = ((j + 1) * WL + 6) / 7;
            float a = v[s];
#pragma unroll
            for (int k = s + 1; k < e; ++k) a = fmaxf(a, v[k]);
            m[j] = a;
        }
#pragma unroll
        for (int i = 0; i < 7; ++i) {
            if (h >= hs[i] && h < he[i]) {        // uniform scalar branch
#pragma unroll
                for (int j = 0; j < 7; ++j)
                    acc[i][j] = fmaxf(acc[i][j], m[j]);
            }
        }
    }
}

// ---------- phase 2: pool from [HW][C], reading only chunk bc ----------
__global__ __launch_bounds__(256) void pool_kernel(
    const float* __restrict__ ft,        // [H][W][C]
    const int4*  __restrict__ rois,      // [R] (x1,y1,x2,y2) image px
    float* __restrict__ out,             // [R,C,7,7]
    int nblocks)
{
    __shared__ __align__(16) float lds[4][32 * 49];
    int wslot = threadIdx.x >> 6;
    int b = __builtin_amdgcn_readfirstlane(blockIdx.x);
    if (b >= nblocks) return;
    int lane = threadIdx.x & 63;

    int bc = b & 7;                      // channel chunk == this XCD
    int g  = b >> 3;                     // ROI group (4 ROIs per block)
    int r  = g * 4 + wslot;              // this wave's ROI
    int c0 = bc << 6;                    // 64-channel chunk base

    int4 roi = rois[r];                  // uniform -> s_load
    // (px * 1/16.f) truncated == px >> 4 for px in [0,1024): exact in fp32.
    int x1 = roi.x >> 4, y1 = roi.y >> 4, x2 = roi.z >> 4, y2 = roi.w >> 4;
    int hl = y2 - y1 + 1, wl = x2 - x1 + 1;   // 2..9 each (bw,bh >= 16 px)

    // h-bins (uniform -> SGPR): [floor(i*hl/7), ceil((i+1)*hl/7)) + y1.
    int hs[7], he[7];
#pragma unroll
    for (int i = 0; i < 7; ++i) {
        hs[i] = y1 + (i * hl) / 7;
        he[i] = y1 + ((i + 1) * hl + 6) / 7;
    }

    float acc[7][7];
#pragma unroll
    for (int i = 0; i < 7; ++i)
#pragma unroll
        for (int j = 0; j < 7; ++j) acc[i][j] = NEG;

    const float* fbase = ft + c0 + lane;
    switch (wl) {                        // wave-uniform dispatch
        case 2: pool_rows<2>(fbase, y1, y2, x1, hs, he, acc); break;
        case 3: pool_rows<3>(fbase, y1, y2, x1, hs, he, acc); break;
        case 4: pool_rows<4>(fbase, y1, y2, x1, hs, he, acc); break;
        case 5: pool_rows<5>(fbase, y1, y2, x1, hs, he, acc); break;
        case 6: pool_rows<6>(fbase, y1, y2, x1, hs, he, acc); break;
        case 7: pool_rows<7>(fbase, y1, y2, x1, hs, he, acc); break;
        case 8: pool_rows<8>(fbase, y1, y2, x1, hs, he, acc); break;
        default: pool_rows<9>(fbase, y1, y2, x1, hs, he, acc); break;
    }

    // Store: transpose [64ch][49] -> flat [c][bin] via LDS, 2 rounds of 32ch.
    float* L  = lds[wslot];
    float* ob = out + ((size_t)r * CC + c0) * 49;
#pragma unroll
    for (int round = 0; round < 2; ++round) {
        if ((lane >> 5) == round) {
            float* p = L + (lane & 31) * 49;      // stride 49 (odd): conflict-free
#pragma unroll
            for (int i = 0; i < 7; ++i)
#pragma unroll
                for (int j = 0; j < 7; ++j) p[i * 7 + j] = acc[i][j];
        }
        asm volatile("s_waitcnt lgkmcnt(0)" ::: "memory");
        float* og = ob + round * 1568;            // 1568 floats contiguous
#pragma unroll
        for (int s = 0; s < 6; ++s) {             // 6 x (64 lanes x dwordx4)
            int idx = s * 64 + lane;
            __builtin_nontemporal_store(*(const f4*)(L + idx * 4),
                                        (f4*)(og + idx * 4));
        }
        if (lane < 8) {                           // 392 = 6*64 + 8 tail
            int idx = 384 + lane;
            __builtin_nontemporal_store(*(const f4*)(L + idx * 4),
                                        (f4*)(og + idx * 4));
        }
        asm volatile("s_waitcnt lgkmcnt(0)" ::: "memory"); // reads done before re-write
    }
}

// ---------- fallback (R4, proven): used only if ws_size < 8 MB ----------
__global__ __launch_bounds__(256) void roi_pool_direct(
    const float* __restrict__ features, const int4* __restrict__ rois,
    float* __restrict__ out, int ngroups)
{
    int wid = __builtin_amdgcn_readfirstlane(
        blockIdx.x * (blockDim.x >> 6) + (threadIdx.x >> 6));
    if (wid >= ngroups) return;
    int lane = threadIdx.x & 63;
    if (lane >= 49) return;
    int r = wid >> 4, c0 = (wid & 15) * 32;
    int4 roi = rois[r];
    int x1 = roi.x >> 4, y1 = roi.y >> 4, x2 = roi.z >> 4, y2 = roi.w >> 4;
    int h_len = y2 - y1 + 1, w_len = x2 - x1 + 1;
    int oh = lane / 7, ow = lane - oh * 7;
    int hs = y1 + (oh * h_len) / 7, he = y1 + ((oh + 1) * h_len + 6) / 7;
    int ws = x1 + (ow * w_len) / 7, we = x1 + ((ow + 1) * w_len + 6) / 7;
    int wlst = we - 1;
    int wa = ws, wb = min(ws + 1, wlst), wc = min(ws + 2, wlst);
    bool need1 = hs + 1 < he, need2 = hs + 2 < he;
    int o0 = (hs * WW + wa) * 4, o0b = (hs * WW + wb) * 4, o0c = (hs * WW + wc) * 4;
    const char* fb = (const char*)features + (size_t)c0 * (HW * 4);
    float* ob = out + ((size_t)r * CC + c0) * 49 + lane;
#pragma unroll 4
    for (int j = 0; j < 32; ++j) {
        float a = fmaxf(fmaxf(*(const float*)(fb + o0),
                              *(const float*)(fb + o0b)),
                        *(const float*)(fb + o0c));
        if (need1) {
            a = fmaxf(a, fmaxf(fmaxf(*(const float*)(fb + o0 + WW * 4),
                                     *(const float*)(fb + o0b + WW * 4)),
                               *(const float*)(fb + o0c + WW * 4)));
        }
        if (need2) {
            a = fmaxf(a, fmaxf(fmaxf(*(const float*)(fb + o0 + 2 * WW * 4),
                                     *(const float*)(fb + o0b + 2 * WW * 4)),
                               *(const float*)(fb + o0c + 2 * WW * 4)));
        }
        *ob = a;
        fb += HW * 4;
        ob += 49;
    }
}

extern "C" void kernel_launch(void* const* d_in, const int* in_sizes, int n_in,
                              void* d_out, int out_size, void* d_ws, size_t ws_size,
                              hipStream_t stream) {
    const float* features = (const float*)d_in[0];   // [1,512,64,64] fp32
    const int4*  rois     = (const int4*)d_in[1];    // [R,4] int32
    float* out = (float*)d_out;
    int R = out_size / (CC * 49);                    // 1024

    if (ws_size >= (size_t)CC * HW * sizeof(float)) {
        float* ft = (float*)d_ws;                    // [HW][C], 8 MB
        transpose_kernel<<<512, 256, 0, stream>>>(features, ft);
        int nblocks = (R / 4) * 8;                   // g*8 + bc, 2048 blocks
        pool_kernel<<<nblocks, 256, 0, stream>>>(ft, rois, out, nblocks);
    } else {
        int ngroups = R * 16;
        roi_pool_direct<<<(ngroups + 3) / 4, 256, 0, stream>>>(features, rois, out, ngroups);
    }
}

// Round 14
// 29.361 us; speedup vs baseline: 1.4879x; 1.0822x over previous
//
#include <hip/hip_runtime.h>
#include <float.h>

// ROI adaptive max-pool 7x7. features [512,64,64] fp32, 1024 ROIs.
// == R13 champion (31.8us) + ONE delta: the pool row phase is specialized on
// BOTH wave-uniform extents: template<WL,HL> (64 instantiations, one uniform
// switch). With HL compile-time the row loop FULLY UNROLLS: h-bin divisions
// vanish, the per-row h-fold folds to constants (branch-free load+fmax DAG),
// and the compiler hoists later rows' loads over earlier rows' compute
// (latency hiding that manual ping-pong (R7) failed to buy).
// Phase 1: transpose features to [H][W][C] in d_ws, block id = bs*8+bc so
//   channel slice bc is WRITTEN by XCD bc (R9-proven L2 co-location).
// Phase 2: pool; block id = g*8+bc, 4 waves = 4 ROIs x the SAME 64-channel
//   chunk -> ft reads hit local XCD L2. Non-temporal output stores
//   (R11-proven: out is never re-read, must not evict ft from L2).
constexpr int CC = 512, HH = 64, WW = 64, HW = HH * WW;
#define NEG (-FLT_MAX)
typedef float f4 __attribute__((ext_vector_type(4)));

// ---------- phase 1: [C][HW] -> [HW][C], XCD-keyed by channel chunk ----------
__global__ __launch_bounds__(256) void transpose_kernel(
    const float* __restrict__ f, float* __restrict__ ft)
{
    __shared__ float tile[64][65];
    int bc = blockIdx.x & 7;             // channel slice -> XCD bc
    int bs = blockIdx.x >> 3;            // hw tile (4096/64)
    int tx = threadIdx.x & 63, ty0 = threadIdx.x >> 6;
#pragma unroll
    for (int k = 0; k < 16; ++k) {
        int c = k * 4 + ty0;
        tile[c][tx] = __builtin_nontemporal_load(
            &f[(size_t)(bc * 64 + c) * HW + bs * 64 + tx]);          // read-once
    }
    __syncthreads();
#pragma unroll
    for (int k = 0; k < 16; ++k) {
        int s = k * 4 + ty0;
        ft[(size_t)(bs * 64 + s) * CC + bc * 64 + tx] = tile[tx][s]; // cached: pool re-reads
    }
}

// ---------- fully-specialized row phase: all windows compile-time ----------
template <int WL, int HL>
__device__ __forceinline__ void pool_rows(
    const float* __restrict__ fbase,     // ft + c0 + lane
    int y1, int x1,
    float (&acc)[7][7])
{
#pragma unroll
    for (int t = 0; t < HL; ++t) {       // FULL unroll: branch-free DAG
        const float* rowp = fbase + (size_t)(y1 + t) * (WW * CC);
        float v[WL];
#pragma unroll
        for (int k = 0; k < WL; ++k)     // exactly WL coalesced loads
            v[k] = rowp[(x1 + k) * CC];
        float m[7];
#pragma unroll
        for (int j = 0; j < 7; ++j) {    // constant w-windows: pure fmax tree
            const int s = (j * WL) / 7;
            const int e = ((j + 1) * WL + 6) / 7;
            float a = v[s];
#pragma unroll
            for (int k = s + 1; k < e; ++k) a = fmaxf(a, v[k]);
            m[j] = a;
        }
#pragma unroll
        for (int i = 0; i < 7; ++i) {    // constant h-windows: folds away
            if (t >= (i * HL) / 7 && t < ((i + 1) * HL + 6) / 7) {
#pragma unroll
                for (int j = 0; j < 7; ++j)
                    acc[i][j] = fmaxf(acc[i][j], m[j]);
            }
        }
    }
}

// ---------- phase 2: pool from [HW][C], reading only chunk bc ----------
__global__ __launch_bounds__(256) void pool_kernel(
    const float* __restrict__ ft,        // [H][W][C]
    const int4*  __restrict__ rois,      // [R] (x1,y1,x2,y2) image px
    float* __restrict__ out,             // [R,C,7,7]
    int nblocks)
{
    __shared__ __align__(16) float lds[4][32 * 49];
    int wslot = threadIdx.x >> 6;
    int b = __builtin_amdgcn_readfirstlane(blockIdx.x);
    if (b >= nblocks) return;
    int lane = threadIdx.x & 63;

    int bc = b & 7;                      // channel chunk == this XCD
    int g  = b >> 3;                     // ROI group (4 ROIs per block)
    int r  = g * 4 + wslot;              // this wave's ROI
    int c0 = bc << 6;                    // 64-channel chunk base

    int4 roi = rois[r];                  // uniform -> s_load
    // (px * 1/16.f) truncated == px >> 4 for px in [0,1024): exact in fp32.
    int x1 = roi.x >> 4, y1 = roi.y >> 4, x2 = roi.z >> 4, y2 = roi.w >> 4;
    int hl = y2 - y1 + 1, wl = x2 - x1 + 1;   // 2..9 each (16<=bw,bh<128)
    // safety clamp (keeps switch total): construction guarantees [2,9]
    wl = min(max(wl, 2), 9);
    hl = min(max(hl, 2), 9);

    float acc[7][7];
#pragma unroll
    for (int i = 0; i < 7; ++i)
#pragma unroll
        for (int j = 0; j < 7; ++j) acc[i][j] = NEG;

    const float* fbase = ft + c0 + lane;
#define POOL_CASE(W, H) \
    case ((W - 2) * 8 + (H - 2)): pool_rows<W, H>(fbase, y1, x1, acc); break;
#define POOL_CASES_W(W) \
    POOL_CASE(W, 2) POOL_CASE(W, 3) POOL_CASE(W, 4) POOL_CASE(W, 5) \
    POOL_CASE(W, 6) POOL_CASE(W, 7) POOL_CASE(W, 8) POOL_CASE(W, 9)
    switch ((wl - 2) * 8 + (hl - 2)) {   // wave-uniform dispatch
        POOL_CASES_W(2) POOL_CASES_W(3) POOL_CASES_W(4) POOL_CASES_W(5)
        POOL_CASES_W(6) POOL_CASES_W(7) POOL_CASES_W(8) POOL_CASES_W(9)
        default: break;                  // unreachable
    }
#undef POOL_CASES_W
#undef POOL_CASE

    // Store: transpose [64ch][49] -> flat [c][bin] via LDS, 2 rounds of 32ch.
    float* L  = lds[wslot];
    float* ob = out + ((size_t)r * CC + c0) * 49;
#pragma unroll
    for (int round = 0; round < 2; ++round) {
        if ((lane >> 5) == round) {
            float* p = L + (lane & 31) * 49;      // stride 49 (odd): conflict-free
#pragma unroll
            for (int i = 0; i < 7; ++i)
#pragma unroll
                for (int j = 0; j < 7; ++j) p[i * 7 + j] = acc[i][j];
        }
        asm volatile("s_waitcnt lgkmcnt(0)" ::: "memory");
        float* og = ob + round * 1568;            // 1568 floats contiguous
#pragma unroll
        for (int s = 0; s < 6; ++s) {             // 6 x (64 lanes x dwordx4)
            int idx = s * 64 + lane;
            __builtin_nontemporal_store(*(const f4*)(L + idx * 4),
                                        (f4*)(og + idx * 4));
        }
        if (lane < 8) {                           // 392 = 6*64 + 8 tail
            int idx = 384 + lane;
            __builtin_nontemporal_store(*(const f4*)(L + idx * 4),
                                        (f4*)(og + idx * 4));
        }
        asm volatile("s_waitcnt lgkmcnt(0)" ::: "memory"); // reads done before re-write
    }
}

// ---------- fallback (R4, proven): used only if ws_size < 8 MB ----------
__global__ __launch_bounds__(256) void roi_pool_direct(
    const float* __restrict__ features, const int4* __restrict__ rois,
    float* __restrict__ out, int ngroups)
{
    int wid = __builtin_amdgcn_readfirstlane(
        blockIdx.x * (blockDim.x >> 6) + (threadIdx.x >> 6));
    if (wid >= ngroups) return;
    int lane = threadIdx.x & 63;
    if (lane >= 49) return;
    int r = wid >> 4, c0 = (wid & 15) * 32;
    int4 roi = rois[r];
    int x1 = roi.x >> 4, y1 = roi.y >> 4, x2 = roi.z >> 4, y2 = roi.w >> 4;
    int h_len = y2 - y1 + 1, w_len = x2 - x1 + 1;
    int oh = lane / 7, ow = lane - oh * 7;
    int hs = y1 + (oh * h_len) / 7, he = y1 + ((oh + 1) * h_len + 6) / 7;
    int ws = x1 + (ow * w_len) / 7, we = x1 + ((ow + 1) * w_len + 6) / 7;
    int wlst = we - 1;
    int wa = ws, wb = min(ws + 1, wlst), wc = min(ws + 2, wlst);
    bool need1 = hs + 1 < he, need2 = hs + 2 < he;
    int o0 = (hs * WW + wa) * 4, o0b = (hs * WW + wb) * 4, o0c = (hs * WW + wc) * 4;
    const char* fb = (const char*)features + (size_t)c0 * (HW * 4);
    float* ob = out + ((size_t)r * CC + c0) * 49 + lane;
#pragma unroll 4
    for (int j = 0; j < 32; ++j) {
        float a = fmaxf(fmaxf(*(const float*)(fb + o0),
                              *(const float*)(fb + o0b)),
                        *(const float*)(fb + o0c));
        if (need1) {
            a = fmaxf(a, fmaxf(fmaxf(*(const float*)(fb + o0 + WW * 4),
                                     *(const float*)(fb + o0b + WW * 4)),
                               *(const float*)(fb + o0c + WW * 4)));
        }
        if (need2) {
            a = fmaxf(a, fmaxf(fmaxf(*(const float*)(fb + o0 + 2 * WW * 4),
                                     *(const float*)(fb + o0b + 2 * WW * 4)),
                               *(const float*)(fb + o0c + 2 * WW * 4)));
        }
        *ob = a;
        fb += HW * 4;
        ob += 49;
    }
}

extern "C" void kernel_launch(void* const* d_in, const int* in_sizes, int n_in,
                              void* d_out, int out_size, void* d_ws, size_t ws_size,
                              hipStream_t stream) {
    const float* features = (const float*)d_in[0];   // [1,512,64,64] fp32
    const int4*  rois     = (const int4*)d_in[1];    // [R,4] int32
    float* out = (float*)d_out;
    int R = out_size / (CC * 49);                    // 1024

    if (ws_size >= (size_t)CC * HW * sizeof(float)) {
        float* ft = (float*)d_ws;                    // [HW][C], 8 MB
        transpose_kernel<<<512, 256, 0, stream>>>(features, ft);
        int nblocks = (R / 4) * 8;                   // g*8 + bc, 2048 blocks
        pool_kernel<<<nblocks, 256, 0, stream>>>(ft, rois, out, nblocks);
    } else {
        int ngroups = R * 16;
        roi_pool_direct<<<(ngroups + 3) / 4, 256, 0, stream>>>(features, rois, out, ngroups);
    }
}